// Round 8
// baseline (4666.819 us; speedup 1.0000x reference)
//
#include <hip/hip_runtime.h>
#include <math.h>

#define NN_ 200000
#define EE_ 400000
#define HH  96
#define LL  6
#define BB  4096
#define SCAN_B 1024
#define NB_SCAN 196   // cdiv(200000, 1024)

typedef short s8v __attribute__((ext_vector_type(8)));
typedef float f4v __attribute__((ext_vector_type(4)));

static inline int cdiv(int a, int b) { return (a + b - 1) / b; }

__device__ __forceinline__ float sigmoidf_(float x) { return 1.0f / (1.0f + __expf(-x)); }
__device__ __forceinline__ float tanhf_(float x) { return 1.0f - 2.0f / (__expf(2.0f * x) + 1.0f); }
__device__ __forceinline__ unsigned short f2bf(float x) {
    unsigned u = __float_as_uint(x);
    unsigned r = u + 0x7FFF + ((u >> 16) & 1);   // RNE
    return (unsigned short)(r >> 16);
}
__device__ __forceinline__ float bf2f(unsigned short u) {
    return __uint_as_float(((unsigned)u) << 16);
}
// load 8 consecutive fp32 and convert to a bf16x8 MFMA fragment (in-register)
__device__ __forceinline__ s8v load_bf8(const float* __restrict__ p) {
    float4 v0 = *(const float4*)p;
    float4 v1 = *(const float4*)(p + 4);
    s8v r;
    r[0] = (short)f2bf(v0.x); r[1] = (short)f2bf(v0.y);
    r[2] = (short)f2bf(v0.z); r[3] = (short)f2bf(v0.w);
    r[4] = (short)f2bf(v1.x); r[5] = (short)f2bf(v1.y);
    r[6] = (short)f2bf(v1.z); r[7] = (short)f2bf(v1.w);
    return r;
}

// ---------------------------------------------------------------------------
// MLP weight pack (old fragment order, read from global in gemm_mlp_mfma):
// Bp[((k>>5)*N + n)*32 + ((k>>3)&3)*8 + (k&7)] = bf16(B[k*N + n])
// ---------------------------------------------------------------------------
__global__ void packB_k(const float* __restrict__ B, unsigned short* __restrict__ Bp,
                        int K, int N)
{
    int idx = blockIdx.x * 256 + threadIdx.x;
    if (idx >= K * N) return;
    int k = idx / N, n = idx % N;
    Bp[(((size_t)(k >> 5) * N + n) * 4 + ((k >> 3) & 3)) * 8 + (k & 7)] = f2bf(B[idx]);
}

// ---------------------------------------------------------------------------
// Wp pack, lane-contiguous LDS order:
// offset = (((l*3+ks)*6 + w)*64 + lane)*8 + j  holds  W[l][k=ks*32+quad*8+j][n=w*16+lc]
// (lane = quad*16+lc). A wave reading tile w does ds_read_b128 at (tile*64+lane)*16B
// -> fully conflict-free.
// ---------------------------------------------------------------------------
__global__ void packWp_k(const float* __restrict__ W, unsigned short* __restrict__ Wp)
{
    int idx = blockIdx.x * 256 + threadIdx.x;
    if (idx >= LL * 3 * 6 * 64 * 8) return;
    int j    = idx & 7;
    int lane = (idx >> 3) & 63;
    int rest = idx >> 9;
    int w  = rest % 6;
    int ks = (rest / 6) % 3;
    int l  = rest / 18;
    int quad = lane >> 4, lc = lane & 15;
    int k = ks * 32 + quad * 8 + j;
    int n = w * 16 + lc;
    Wp[idx] = f2bf(W[(size_t)l * 9216 + (size_t)k * 96 + n]);
}

// ---------------------------------------------------------------------------
// Wgp pack, gate-interleaved + lane-contiguous:
// tile T = w*4 + g (w=j-block 0..5, g=gate 0..3); column n = g*96 + w*16 + lc.
// offset = ((ks*24 + T)*64 + lane)*8 + j  holds  Wg[k=ks*32+quad*8+j][n]
// Wg semantics: k<96 from wih (agg side), k>=96 from whh (h side);
// n in [0,192): r/z sums; [192,288): i_n (wih only); [288,384): h_n (whh only)
// ---------------------------------------------------------------------------
__global__ void packWgp_k(const float* __restrict__ wih, const float* __restrict__ whh,
                          unsigned short* __restrict__ Wgp)
{
    int idx = blockIdx.x * 256 + threadIdx.x;
    if (idx >= 6 * 24 * 64 * 8) return;
    int j    = idx & 7;
    int lane = (idx >> 3) & 63;
    int rest = idx >> 9;
    int T  = rest % 24;
    int ks = rest / 24;
    int quad = lane >> 4, lc = lane & 15;
    int g = T & 3, w = T >> 2;
    int k = ks * 32 + quad * 8 + j;
    int n = g * 96 + w * 16 + lc;
    float v;
    if (n < 192) {
        v = (k < 96) ? wih[(size_t)n * 96 + k] : whh[(size_t)n * 96 + (k - 96)];
    } else if (n < 288) {
        int jj = n - 192;
        v = (k < 96) ? wih[(size_t)(192 + jj) * 96 + k] : 0.f;
    } else {
        int jj = n - 288;
        v = (k < 96) ? 0.f : whh[(size_t)(192 + jj) * 96 + (k - 96)];
    }
    Wgp[idx] = f2bf(v);
}

__global__ void pad_k(const float* __restrict__ x, float* __restrict__ h)
{
    int idx = blockIdx.x * 256 + threadIdx.x;
    if (idx >= NN_ * HH) return;
    int n = idx / HH, j = idx % HH;
    h[idx] = (j < 32) ? x[n * 32 + j] : 0.f;
}

// --------------------------- CSR build (once per component) -----------------
__global__ void deg_k(const int* __restrict__ ei, int* __restrict__ deg)
{
    int e = blockIdx.x * 256 + threadIdx.x;
    if (e >= EE_) return;
    atomicAdd(&deg[ei[EE_ + e]], 1);
}

__global__ __launch_bounds__(SCAN_B) void scan1_k(
    const int* __restrict__ deg, int* __restrict__ rp, int* __restrict__ bsum)
{
    __shared__ int sh[SCAN_B];
    int i = blockIdx.x * SCAN_B + threadIdx.x;
    int v = (i < NN_) ? deg[i] : 0;
    sh[threadIdx.x] = v;
    __syncthreads();
    for (int off = 1; off < SCAN_B; off <<= 1) {
        int t = (threadIdx.x >= off) ? sh[threadIdx.x - off] : 0;
        __syncthreads();
        sh[threadIdx.x] += t;
        __syncthreads();
    }
    if (i < NN_) rp[i] = sh[threadIdx.x] - v;     // exclusive within block
    if (threadIdx.x == SCAN_B - 1) bsum[blockIdx.x] = sh[threadIdx.x];
}

__global__ __launch_bounds__(256) void scan2_k(int* __restrict__ bsum)
{
    __shared__ int sh[256];
    int v = (threadIdx.x < NB_SCAN) ? bsum[threadIdx.x] : 0;
    sh[threadIdx.x] = v;
    __syncthreads();
    for (int off = 1; off < 256; off <<= 1) {
        int t = (threadIdx.x >= off) ? sh[threadIdx.x - off] : 0;
        __syncthreads();
        sh[threadIdx.x] += t;
        __syncthreads();
    }
    if (threadIdx.x < NB_SCAN) bsum[threadIdx.x] = sh[threadIdx.x] - v;  // exclusive
}

__global__ void scan3_k(int* __restrict__ rp, const int* __restrict__ bsum,
                        int* __restrict__ cur)
{
    int i = blockIdx.x * 256 + threadIdx.x;
    if (i < NN_) {
        int r = rp[i] + bsum[i / SCAN_B];
        rp[i] = r;
        cur[i] = r;
    }
    if (i == 0) rp[NN_] = EE_;
}

__global__ void fill_k(const int* __restrict__ ei, int* __restrict__ cur,
                       int* __restrict__ srcs)
{
    int e = blockIdx.x * 256 + threadIdx.x;
    if (e >= EE_) return;
    int s = ei[e];
    int d = ei[EE_ + e];
    int pos = atomicAdd(&cur[d], 1);
    srcs[pos] = s;
}

// batch row pointers: batch[] is sorted, detect segment boundaries.
__global__ void brp_k(const int* __restrict__ bat, int* __restrict__ rpb)
{
    int i = blockIdx.x * 256 + threadIdx.x;
    if (i >= NN_) return;
    int b = bat[i];
    if (i == 0) {
        for (int q = 0; q <= b; q++) rpb[q] = 0;
    } else {
        int p = bat[i - 1];
        for (int q = p + 1; q <= b; q++) rpb[q] = i;
    }
    if (i == NN_ - 1) {
        for (int q = b + 1; q <= BB; q++) rpb[q] = NN_;
    }
}

// ---------------------------------------------------------------------------
// m_bf = bf16( bf16(h) @ W[l] ). Block = 384 thr (6 waves) x 64 rows.
// Wave w computes 64 rows x cols [16w,16w+16): B-frag reused across 4 row
// frags -> 12 MFMA / 3 LDS reads per wave; acc = 16 AGPR. LDS reads are
// lane-contiguous (conflict-free).
// ---------------------------------------------------------------------------
__global__ __launch_bounds__(384) void gemm1_mfma(
    const float* __restrict__ h,
    const unsigned short* __restrict__ Wp,   // this layer's pack: [3][6][64][8]
    unsigned short* __restrict__ m_bf)
{
    __shared__ unsigned short Ws[9216];      // 18,432 B
    int tid  = threadIdx.x;
    int wave = tid >> 6;
    int lane = tid & 63;
    int quad = lane >> 4;
    int lc   = lane & 15;
    int row0 = blockIdx.x * 64;

    {
        const uint4* src = (const uint4*)Wp;
        uint4* dst = (uint4*)Ws;
        #pragma unroll
        for (int i = 0; i < 3; i++) dst[i * 384 + tid] = src[i * 384 + tid];
    }
    __syncthreads();

    f4v acc[4] = {};
    #pragma unroll
    for (int ks = 0; ks < 3; ks++) {
        s8v b = *(const s8v*)(Ws + ((size_t)(ks * 6 + wave) * 64 + lane) * 8);
        #pragma unroll
        for (int r = 0; r < 4; r++) {
            s8v a = load_bf8(h + (size_t)(row0 + r * 16 + lc) * 96 + ks * 32 + quad * 8);
            acc[r] = __builtin_amdgcn_mfma_f32_16x16x32_bf16(a, b, acc[r], 0, 0, 0);
        }
    }
    #pragma unroll
    for (int r = 0; r < 4; r++) {
        #pragma unroll
        for (int i = 0; i < 4; i++) {
            m_bf[(size_t)(row0 + r * 16 + quad * 4 + i) * 96 + wave * 16 + lc] = f2bf(acc[r][i]);
        }
    }
}

// ---------------------------------------------------------------------------
// CSR aggregation: agg_bf[n] = bf16( sum_{e in CSR[n]} m_bf[srcs[e]] ).
// ---------------------------------------------------------------------------
__global__ void agg_csr_k(const unsigned short* __restrict__ m_bf,
                          const int* __restrict__ rp, const int* __restrict__ srcs,
                          unsigned short* __restrict__ agg_bf)
{
    int idx = blockIdx.x * 256 + threadIdx.x;
    if (idx >= NN_ * 12) return;
    int node = idx / 12;
    int g = (idx % 12) * 8;
    int e0 = rp[node], e1 = rp[node + 1];
    float s0 = 0.f, s1 = 0.f, s2 = 0.f, s3 = 0.f;
    float s4 = 0.f, s5 = 0.f, s6 = 0.f, s7 = 0.f;
    for (int e = e0; e < e1; e++) {
        int sr = srcs[e];
        uint4 u = *(const uint4*)(m_bf + (size_t)sr * 96 + g);
        s0 += bf2f((unsigned short)(u.x & 0xFFFF));
        s1 += bf2f((unsigned short)(u.x >> 16));
        s2 += bf2f((unsigned short)(u.y & 0xFFFF));
        s3 += bf2f((unsigned short)(u.y >> 16));
        s4 += bf2f((unsigned short)(u.z & 0xFFFF));
        s5 += bf2f((unsigned short)(u.z >> 16));
        s6 += bf2f((unsigned short)(u.w & 0xFFFF));
        s7 += bf2f((unsigned short)(u.w >> 16));
    }
    uint4 o;
    o.x = (unsigned)f2bf(s0) | ((unsigned)f2bf(s1) << 16);
    o.y = (unsigned)f2bf(s2) | ((unsigned)f2bf(s3) << 16);
    o.z = (unsigned)f2bf(s4) | ((unsigned)f2bf(s5) << 16);
    o.w = (unsigned)f2bf(s6) | ((unsigned)f2bf(s7) << 16);
    *(uint4*)(agg_bf + (size_t)node * 96 + g) = o;
}

// ---------------------------------------------------------------------------
// Fused GRU. Block = 384 thr (6 waves) x 64 rows; wave w owns j in
// [16w,16w+16) with ALL FOUR gate column-tiles (pack T = w*4+g), so the
// GRUCell epilogue stays lane-local. Wgp double-buffered per 32-k slice;
// fragments are lane-contiguous ds_read_b128 (conflict-free). B-frag reused
// across 4 row-frags: 96 MFMA / 24 LDS reads / wave, acc = 64 AGPR.
// Accumulation order identical to Round 6/7 -> bit-identical results.
// ---------------------------------------------------------------------------
__global__ __launch_bounds__(384) void gru_mfma(
    const unsigned short* __restrict__ agg_bf,
    const unsigned short* __restrict__ Wgp,
    const float* __restrict__ bih, const float* __restrict__ bhh,
    float* __restrict__ h)
{
    __shared__ unsigned short Bs[2][12288];  // 2 x 24,576 B
    int tid  = threadIdx.x;
    int wave = tid >> 6;
    int lane = tid & 63;
    int quad = lane >> 4;
    int lc   = lane & 15;
    int row0 = blockIdx.x * 64;

    // stage slice 0 (1536 uint4, 4 per thread)
    {
        const uint4* src = (const uint4*)Wgp;
        uint4* dst = (uint4*)&Bs[0][0];
        #pragma unroll
        for (int i = 0; i < 4; i++) dst[i * 384 + tid] = src[i * 384 + tid];
    }
    __syncthreads();

    f4v acc[4][4] = {};   // [row-frag][gate]
    #pragma unroll
    for (int ks = 0; ks < 6; ks++) {
        if (ks < 5) {   // prefetch next slice into the other buffer
            const uint4* src = (const uint4*)(Wgp + (size_t)(ks + 1) * 12288);
            uint4* dst = (uint4*)&Bs[(ks + 1) & 1][0];
            #pragma unroll
            for (int i = 0; i < 4; i++) dst[i * 384 + tid] = src[i * 384 + tid];
        }
        s8v a[4];
        #pragma unroll
        for (int r = 0; r < 4; r++) {
            int row = row0 + r * 16 + lc;
            if (ks < 3) a[r] = *(const s8v*)(agg_bf + (size_t)row * 96 + ks * 32 + quad * 8);
            else        a[r] = load_bf8(h + (size_t)row * 96 + (ks - 3) * 32 + quad * 8);
        }
        const unsigned short* B = &Bs[ks & 1][0];
        #pragma unroll
        for (int g = 0; g < 4; g++) {
            s8v b = *(const s8v*)(B + ((size_t)(wave * 4 + g) * 64 + lane) * 8);
            #pragma unroll
            for (int r = 0; r < 4; r++) {
                acc[r][g] = __builtin_amdgcn_mfma_f32_16x16x32_bf16(a[r], b, acc[r][g], 0, 0, 0);
            }
        }
        __syncthreads();
    }
    int j = wave * 16 + lc;
    float bi_r = bih[j],       bh_r = bhh[j];
    float bi_z = bih[96 + j],  bh_z = bhh[96 + j];
    float bi_n = bih[192 + j], bh_n = bhh[192 + j];
    #pragma unroll
    for (int r = 0; r < 4; r++) {
        #pragma unroll
        for (int i = 0; i < 4; i++) {
            int row = row0 + r * 16 + quad * 4 + i;
            float rg = sigmoidf_(acc[r][0][i] + bi_r + bh_r);
            float zg = sigmoidf_(acc[r][1][i] + bi_z + bh_z);
            float nn = tanhf_(acc[r][2][i] + bi_n + rg * (acc[r][3][i] + bh_n));
            size_t hi = (size_t)row * 96 + j;
            float hv = h[hi];
            h[hi] = (1.f - zg) * nn + zg * hv;
        }
    }
}

// ---------------------------------------------------------------------------
// Mean pool via sorted-batch segments: one block per graph, no atomics.
// ---------------------------------------------------------------------------
__global__ __launch_bounds__(128) void pool_csr_k(
    const float* __restrict__ h, const int* __restrict__ rpb, float* __restrict__ g)
{
    int b = blockIdx.x;
    int j = threadIdx.x;
    if (j >= 96) return;
    int n0 = rpb[b], n1 = rpb[b + 1];
    float s = 0.f;
    for (int n = n0; n < n1; n++) s += fmaxf(h[(size_t)n * 96 + j], 0.f);
    float c = (float)(n1 - n0);
    g[(size_t)b * 96 + j] = s / fmaxf(c, 1.f);
}

__global__ void feat_k(const float* __restrict__ g1, const float* __restrict__ g2,
                       const float* __restrict__ g3, float* __restrict__ feat)
{
    int idx = blockIdx.x * 256 + threadIdx.x;
    if (idx >= BB * HH) return;
    int b = idx / HH, j = idx % HH;
    float a = g1[idx], bb = g2[idx], c = g3[idx];
    float* f = feat + (size_t)b * 384;
    f[j]       = a;
    f[96 + j]  = bb;
    f[192 + j] = c;
    f[288 + j] = a * bb * c;
}

// ---------------------------------------------------------------------------
// MLP GEMM: C[M,N] = relu(bf16(A[M,K]) @ Bp + bias).
// ---------------------------------------------------------------------------
__global__ __launch_bounds__(256) void gemm_mlp_mfma(
    const float* __restrict__ A, const unsigned short* __restrict__ Bp,
    const float* __restrict__ bias, float* __restrict__ C,
    int K, int N, int doRelu)
{
    int wave = threadIdx.x >> 6;
    int lane = threadIdx.x & 63;
    int quad = lane >> 4;
    int lc   = lane & 15;
    int rowA = blockIdx.y * 64 + wave * 16 + lc;
    int colb = blockIdx.x * 128;

    f4v acc[8] = {};
    for (int ks = 0; ks < K / 32; ks++) {
        s8v a = load_bf8(A + (size_t)rowA * K + ks * 32 + quad * 8);
        #pragma unroll
        for (int t = 0; t < 8; t++) {
            int n = colb + t * 16 + lc;
            s8v b = *(const s8v*)(Bp + ((size_t)(ks * N + n) * 4 + quad) * 8);
            acc[t] = __builtin_amdgcn_mfma_f32_16x16x32_bf16(a, b, acc[t], 0, 0, 0);
        }
    }
    int rowD = blockIdx.y * 64 + wave * 16 + quad * 4;
    #pragma unroll
    for (int t = 0; t < 8; t++) {
        int n = colb + t * 16 + lc;
        float bv = bias[n];
        #pragma unroll
        for (int r = 0; r < 4; r++) {
            float v = acc[t][r] + bv;
            if (doRelu) v = fmaxf(v, 0.f);
            C[(size_t)(rowD + r) * N + n] = v;
        }
    }
}

// fc3: one wave per graph, shuffle reduction.
__global__ __launch_bounds__(256) void fc3_k(const float* __restrict__ t2,
                                             const float* __restrict__ w,
                                             const float* __restrict__ bias,
                                             float* __restrict__ out)
{
    int wave = threadIdx.x >> 6;
    int lane = threadIdx.x & 63;
    int b = blockIdx.x * 4 + wave;
    const float* row = t2 + (size_t)b * 384;
    float a0 = 0.f, a1 = 0.f, a2 = 0.f;
    #pragma unroll
    for (int kk = 0; kk < 6; kk++) {
        int k = kk * 64 + lane;
        float x = row[k];
        a0 += x * w[k * 3 + 0];
        a1 += x * w[k * 3 + 1];
        a2 += x * w[k * 3 + 2];
    }
    #pragma unroll
    for (int off = 32; off > 0; off >>= 1) {
        a0 += __shfl_down(a0, off);
        a1 += __shfl_down(a1, off);
        a2 += __shfl_down(a2, off);
    }
    if (lane == 0) {
        out[b * 3 + 0] = a0 + bias[0];
        out[b * 3 + 1] = a1 + bias[1];
        out[b * 3 + 2] = a2 + bias[2];
    }
}

extern "C" void kernel_launch(void* const* d_in, const int* in_sizes, int n_in,
                              void* d_out, int out_size, void* d_ws, size_t ws_size,
                              hipStream_t stream)
{
    // Workspace (floats). Total ~41.3M f = 165 MB (237 MB proven safe).
    float* ws    = (float*)d_ws;
    float* h     = ws;                               // 19,200,000
    float* mbfF  = h + (size_t)NN_ * HH;             //  9,600,000 (19.2M bf16)
    float* abfF  = mbfF + (size_t)NN_ * HH / 2;      //  9,600,000 (19.2M bf16)
    float* wpF   = abfF + (size_t)NN_ * HH / 2;      //     27,648
    float* wgpF  = wpF + 27648;                      //     36,864
    float* fc1pF = wgpF + 36864;                     //    294,912 (589,824 bf16)
    float* fc2pF = fc1pF + 294912;                   //    294,912
    float* g3    = fc2pF + 294912;                   //  1,179,648
    int*   rp    = (int*)(g3 + 3 * (size_t)BB * HH); //    200,064 ints
    int*   srcs  = rp + 200064;                      //    400,000 ints
    int*   deg   = srcs + 400000;                    //    200,000 ints
    int*   cur   = deg + 200000;                     //    200,000 ints
    int*   bsum  = cur + 200000;                     //        256 ints
    int*   rpb   = bsum + 256;                       //      4,097 ints

    unsigned short* m_bf   = (unsigned short*)mbfF;
    unsigned short* agg_bf = (unsigned short*)abfF;
    unsigned short* Wp     = (unsigned short*)wpF;
    unsigned short* Wgp    = (unsigned short*)wgpF;
    unsigned short* fc1p   = (unsigned short*)fc1pF;
    unsigned short* fc2p   = (unsigned short*)fc2pF;

    // MLP temps alias h (dead after pooling)
    float* feat = h;
    float* t1   = h + 2 * 1024 * 1024;
    float* t2   = h + 9 * 1024 * 1024;

    for (int c = 0; c < 3; c++) {
        const float* x   = (const float*)d_in[c * 8 + 0];
        const int*   ei  = (const int*)  d_in[c * 8 + 1];
        const int*   bat = (const int*)  d_in[c * 8 + 2];
        const float* W   = (const float*)d_in[c * 8 + 3];
        const float* wih = (const float*)d_in[c * 8 + 4];
        const float* whh = (const float*)d_in[c * 8 + 5];
        const float* bih = (const float*)d_in[c * 8 + 6];
        const float* bhh = (const float*)d_in[c * 8 + 7];

        // CSR build (once per component, reused for all 6 layers)
        hipMemsetAsync(deg, 0, NN_ * sizeof(int), stream);
        deg_k<<<cdiv(EE_, 256), 256, 0, stream>>>(ei, deg);
        scan1_k<<<NB_SCAN, SCAN_B, 0, stream>>>(deg, rp, bsum);
        scan2_k<<<1, 256, 0, stream>>>(bsum);
        scan3_k<<<cdiv(NN_, 256), 256, 0, stream>>>(rp, bsum, cur);
        fill_k<<<cdiv(EE_, 256), 256, 0, stream>>>(ei, cur, srcs);
        brp_k<<<cdiv(NN_, 256), 256, 0, stream>>>(bat, rpb);

        packWp_k<<<cdiv(LL * 3 * 6 * 64 * 8, 256), 256, 0, stream>>>(W, Wp);
        packWgp_k<<<cdiv(6 * 24 * 64 * 8, 256), 256, 0, stream>>>(wih, whh, Wgp);
        pad_k<<<cdiv(NN_ * HH, 256), 256, 0, stream>>>(x, h);

        for (int l = 0; l < LL; l++) {
            gemm1_mfma<<<NN_ / 64, 384, 0, stream>>>(h, Wp + (size_t)l * 3 * 6 * 64 * 8, m_bf);
            agg_csr_k<<<cdiv(NN_ * 12, 256), 256, 0, stream>>>(m_bf, rp, srcs, agg_bf);
            gru_mfma<<<NN_ / 64, 384, 0, stream>>>(agg_bf, Wgp, bih, bhh, h);
        }

        pool_csr_k<<<BB, 128, 0, stream>>>(h, rpb, g3 + (size_t)c * BB * HH);
    }

    const float* fc1_w = (const float*)d_in[24];
    const float* fc1_b = (const float*)d_in[25];
    const float* fc2_w = (const float*)d_in[26];
    const float* fc2_b = (const float*)d_in[27];
    const float* fc3_w = (const float*)d_in[28];
    const float* fc3_b = (const float*)d_in[29];

    packB_k<<<cdiv(384 * 1536, 256), 256, 0, stream>>>(fc1_w, fc1p, 384, 1536);
    packB_k<<<cdiv(1536 * 384, 256), 256, 0, stream>>>(fc2_w, fc2p, 1536, 384);

    feat_k<<<cdiv(BB * HH, 256), 256, 0, stream>>>(
        g3, g3 + (size_t)BB * HH, g3 + 2 * (size_t)BB * HH, feat);
    gemm_mlp_mfma<<<dim3(1536 / 128, BB / 64), 256, 0, stream>>>(
        feat, fc1p, fc1_b, t1, 384, 1536, 1);
    gemm_mlp_mfma<<<dim3(384 / 128, BB / 64), 256, 0, stream>>>(
        t1, fc2p, fc2_b, t2, 1536, 384, 1);
    fc3_k<<<BB / 4, 256, 0, stream>>>(t2, fc3_w, fc3_b, (float*)d_out);
}

// Round 9
// 3522.008 us; speedup vs baseline: 1.3250x; 1.3250x over previous
//
#include <hip/hip_runtime.h>
#include <math.h>

#define NN_ 200000
#define EE_ 400000
#define HH  96
#define LL  6
#define BB  4096
#define SCAN_B 1024
#define NB_SCAN 196   // cdiv(200000, 1024)

typedef short s8v __attribute__((ext_vector_type(8)));
typedef float f4v __attribute__((ext_vector_type(4)));

static inline int cdiv(int a, int b) { return (a + b - 1) / b; }

__device__ __forceinline__ float sigmoidf_(float x) { return 1.0f / (1.0f + __expf(-x)); }
__device__ __forceinline__ float tanhf_(float x) { return 1.0f - 2.0f / (__expf(2.0f * x) + 1.0f); }
__device__ __forceinline__ unsigned short f2bf(float x) {
    unsigned u = __float_as_uint(x);
    unsigned r = u + 0x7FFF + ((u >> 16) & 1);   // RNE
    return (unsigned short)(r >> 16);
}
__device__ __forceinline__ float bf2f(unsigned short u) {
    return __uint_as_float(((unsigned)u) << 16);
}
// load 8 consecutive fp32 and convert to a bf16x8 MFMA fragment (in-register)
__device__ __forceinline__ s8v load_bf8(const float* __restrict__ p) {
    float4 v0 = *(const float4*)p;
    float4 v1 = *(const float4*)(p + 4);
    s8v r;
    r[0] = (short)f2bf(v0.x); r[1] = (short)f2bf(v0.y);
    r[2] = (short)f2bf(v0.z); r[3] = (short)f2bf(v0.w);
    r[4] = (short)f2bf(v1.x); r[5] = (short)f2bf(v1.y);
    r[6] = (short)f2bf(v1.z); r[7] = (short)f2bf(v1.w);
    return r;
}

// ---------------------------------------------------------------------------
// MLP weight pack (B-operand fragment order, read from global):
// Bp[((k>>5)*N + n)*32 + ((k>>3)&3)*8 + (k&7)] = bf16(B[k*N + n])
// ---------------------------------------------------------------------------
__global__ void packB_k(const float* __restrict__ B, unsigned short* __restrict__ Bp,
                        int K, int N)
{
    int idx = blockIdx.x * 256 + threadIdx.x;
    if (idx >= K * N) return;
    int k = idx / N, n = idx % N;
    Bp[(((size_t)(k >> 5) * N + n) * 4 + ((k >> 3) & 3)) * 8 + (k & 7)] = f2bf(B[idx]);
}

// ---------------------------------------------------------------------------
// Wp pack, weight-stationary A-operand order:
// offset = (((l*6 + jb)*3 + ks)*64 + lane)*8 + j
//   holds  W[l][k = ks*32 + (lane>>4)*8 + j][n = jb*16 + (lane&15)]
// A wave's fragment load = 64 lanes x 16B consecutive (1 KB) from L2.
// ---------------------------------------------------------------------------
__global__ void packWp_k(const float* __restrict__ W, unsigned short* __restrict__ Wp)
{
    int idx = blockIdx.x * 256 + threadIdx.x;
    if (idx >= LL * 6 * 3 * 64 * 8) return;
    int j    = idx & 7;
    int lane = (idx >> 3) & 63;
    int rest = idx >> 9;
    int ks = rest % 3;
    int jb = (rest / 3) % 6;
    int l  = rest / 18;
    int quad = lane >> 4, lc = lane & 15;
    int k = ks * 32 + quad * 8 + j;
    int n = jb * 16 + lc;
    Wp[idx] = f2bf(W[(size_t)l * 9216 + (size_t)k * 96 + n]);
}

// ---------------------------------------------------------------------------
// Wgp pack, weight-stationary A-operand order, gate-interleaved:
// T = jb*4 + g;  offset = ((T*6 + ks)*64 + lane)*8 + j
//   holds  Wg[k = ks*32 + quad*8 + j][n = g*96 + jb*16 + lc]
// Wg semantics: k<96 from wih (agg side), k>=96 from whh (h side);
// n in [0,192): r/z sums; [192,288): i_n (wih only); [288,384): h_n (whh only)
// ---------------------------------------------------------------------------
__global__ void packWgp_k(const float* __restrict__ wih, const float* __restrict__ whh,
                          unsigned short* __restrict__ Wgp)
{
    int idx = blockIdx.x * 256 + threadIdx.x;
    if (idx >= 24 * 6 * 64 * 8) return;
    int j    = idx & 7;
    int lane = (idx >> 3) & 63;
    int rest = idx >> 9;
    int ks = rest % 6;
    int T  = rest / 6;
    int quad = lane >> 4, lc = lane & 15;
    int g = T & 3, jb = T >> 2;
    int k = ks * 32 + quad * 8 + j;
    int n = g * 96 + jb * 16 + lc;
    float v;
    if (n < 192) {
        v = (k < 96) ? wih[(size_t)n * 96 + k] : whh[(size_t)n * 96 + (k - 96)];
    } else if (n < 288) {
        int jj = n - 192;
        v = (k < 96) ? wih[(size_t)(192 + jj) * 96 + k] : 0.f;
    } else {
        int jj = n - 288;
        v = (k < 96) ? 0.f : whh[(size_t)(192 + jj) * 96 + (k - 96)];
    }
    Wgp[idx] = f2bf(v);
}

// combined bias pack: bs[0..95]=bih_r+bhh_r, [96..191]=bih_z+bhh_z,
// [192..287]=bih_n, [288..383]=bhh_n
__global__ void bpack_k(const float* __restrict__ bih, const float* __restrict__ bhh,
                        float* __restrict__ bs)
{
    int j = threadIdx.x;
    if (j >= 96) return;
    bs[j]        = bih[j] + bhh[j];
    bs[96 + j]   = bih[96 + j] + bhh[96 + j];
    bs[192 + j]  = bih[192 + j];
    bs[288 + j]  = bhh[192 + j];
}

__global__ void pad_k(const float* __restrict__ x, float* __restrict__ h)
{
    int idx = blockIdx.x * 256 + threadIdx.x;
    if (idx >= NN_ * HH) return;
    int n = idx / HH, j = idx % HH;
    h[idx] = (j < 32) ? x[n * 32 + j] : 0.f;
}

// --------------------------- CSR build (once per component) -----------------
__global__ void deg_k(const int* __restrict__ ei, int* __restrict__ deg)
{
    int e = blockIdx.x * 256 + threadIdx.x;
    if (e >= EE_) return;
    atomicAdd(&deg[ei[EE_ + e]], 1);
}

__global__ __launch_bounds__(SCAN_B) void scan1_k(
    const int* __restrict__ deg, int* __restrict__ rp, int* __restrict__ bsum)
{
    __shared__ int sh[SCAN_B];
    int i = blockIdx.x * SCAN_B + threadIdx.x;
    int v = (i < NN_) ? deg[i] : 0;
    sh[threadIdx.x] = v;
    __syncthreads();
    for (int off = 1; off < SCAN_B; off <<= 1) {
        int t = (threadIdx.x >= off) ? sh[threadIdx.x - off] : 0;
        __syncthreads();
        sh[threadIdx.x] += t;
        __syncthreads();
    }
    if (i < NN_) rp[i] = sh[threadIdx.x] - v;     // exclusive within block
    if (threadIdx.x == SCAN_B - 1) bsum[blockIdx.x] = sh[threadIdx.x];
}

__global__ __launch_bounds__(256) void scan2_k(int* __restrict__ bsum)
{
    __shared__ int sh[256];
    int v = (threadIdx.x < NB_SCAN) ? bsum[threadIdx.x] : 0;
    sh[threadIdx.x] = v;
    __syncthreads();
    for (int off = 1; off < 256; off <<= 1) {
        int t = (threadIdx.x >= off) ? sh[threadIdx.x - off] : 0;
        __syncthreads();
        sh[threadIdx.x] += t;
        __syncthreads();
    }
    if (threadIdx.x < NB_SCAN) bsum[threadIdx.x] = sh[threadIdx.x] - v;  // exclusive
}

__global__ void scan3_k(int* __restrict__ rp, const int* __restrict__ bsum,
                        int* __restrict__ cur)
{
    int i = blockIdx.x * 256 + threadIdx.x;
    if (i < NN_) {
        int r = rp[i] + bsum[i / SCAN_B];
        rp[i] = r;
        cur[i] = r;
    }
    if (i == 0) rp[NN_] = EE_;
}

__global__ void fill_k(const int* __restrict__ ei, int* __restrict__ cur,
                       int* __restrict__ srcs)
{
    int e = blockIdx.x * 256 + threadIdx.x;
    if (e >= EE_) return;
    int s = ei[e];
    int d = ei[EE_ + e];
    int pos = atomicAdd(&cur[d], 1);
    srcs[pos] = s;
}

// batch row pointers: batch[] is sorted, detect segment boundaries.
__global__ void brp_k(const int* __restrict__ bat, int* __restrict__ rpb)
{
    int i = blockIdx.x * 256 + threadIdx.x;
    if (i >= NN_) return;
    int b = bat[i];
    if (i == 0) {
        for (int q = 0; q <= b; q++) rpb[q] = 0;
    } else {
        int p = bat[i - 1];
        for (int q = p + 1; q <= b; q++) rpb[q] = i;
    }
    if (i == NN_ - 1) {
        for (int q = b + 1; q <= BB; q++) rpb[q] = NN_;
    }
}

// ---------------------------------------------------------------------------
// m_bf = bf16( bf16(h) @ W[l] ) — weight-stationary, no LDS, no barriers.
// Block = 128 thr (2 waves); wave owns 32 nodes (2 tiles of 16) exclusively.
// Data frags held in regs; W-frags are lane-contiguous 1 KB L2 reads.
// D[m=out-col][n=node]: col=lane&15 -> node, row=quad*4+i -> j-offset.
// ---------------------------------------------------------------------------
__global__ __launch_bounds__(128) void gemm1_mfma(
    const float* __restrict__ h,
    const unsigned short* __restrict__ Wp,   // this layer's pack: [6][3][64][8]
    unsigned short* __restrict__ m_bf)
{
    int wave = threadIdx.x >> 6;
    int lane = threadIdx.x & 63;
    int quad = lane >> 4;
    int lc   = lane & 15;
    int nT0  = blockIdx.x * 4 + wave * 2;    // node-tile base (16 nodes/tile)

    s8v d[2][3];
    #pragma unroll
    for (int t = 0; t < 2; t++) {
        int node = (nT0 + t) * 16 + lc;
        #pragma unroll
        for (int ks = 0; ks < 3; ks++)
            d[t][ks] = load_bf8(h + (size_t)node * 96 + ks * 32 + quad * 8);
    }
    for (int jb = 0; jb < 6; jb++) {
        f4v acc[2] = {};
        #pragma unroll
        for (int ks = 0; ks < 3; ks++) {
            s8v w = *(const s8v*)(Wp + ((size_t)(jb * 3 + ks) * 64 + lane) * 8);
            acc[0] = __builtin_amdgcn_mfma_f32_16x16x32_bf16(w, d[0][ks], acc[0], 0, 0, 0);
            acc[1] = __builtin_amdgcn_mfma_f32_16x16x32_bf16(w, d[1][ks], acc[1], 0, 0, 0);
        }
        #pragma unroll
        for (int t = 0; t < 2; t++) {
            int node = (nT0 + t) * 16 + lc;
            unsigned short o[4];
            #pragma unroll
            for (int i = 0; i < 4; i++) o[i] = f2bf(acc[t][i]);
            *(uint2*)(m_bf + (size_t)node * 96 + jb * 16 + quad * 4) =
                make_uint2((unsigned)o[0] | ((unsigned)o[1] << 16),
                           (unsigned)o[2] | ((unsigned)o[3] << 16));
        }
    }
}

// ---------------------------------------------------------------------------
// CSR aggregation: agg_bf[n] = bf16( sum_{e in CSR[n]} m_bf[srcs[e]] ).
// ---------------------------------------------------------------------------
__global__ void agg_csr_k(const unsigned short* __restrict__ m_bf,
                          const int* __restrict__ rp, const int* __restrict__ srcs,
                          unsigned short* __restrict__ agg_bf)
{
    int idx = blockIdx.x * 256 + threadIdx.x;
    if (idx >= NN_ * 12) return;
    int node = idx / 12;
    int g = (idx % 12) * 8;
    int e0 = rp[node], e1 = rp[node + 1];
    float s0 = 0.f, s1 = 0.f, s2 = 0.f, s3 = 0.f;
    float s4 = 0.f, s5 = 0.f, s6 = 0.f, s7 = 0.f;
    for (int e = e0; e < e1; e++) {
        int sr = srcs[e];
        uint4 u = *(const uint4*)(m_bf + (size_t)sr * 96 + g);
        s0 += bf2f((unsigned short)(u.x & 0xFFFF));
        s1 += bf2f((unsigned short)(u.x >> 16));
        s2 += bf2f((unsigned short)(u.y & 0xFFFF));
        s3 += bf2f((unsigned short)(u.y >> 16));
        s4 += bf2f((unsigned short)(u.z & 0xFFFF));
        s5 += bf2f((unsigned short)(u.z >> 16));
        s6 += bf2f((unsigned short)(u.w & 0xFFFF));
        s7 += bf2f((unsigned short)(u.w >> 16));
    }
    uint4 o;
    o.x = (unsigned)f2bf(s0) | ((unsigned)f2bf(s1) << 16);
    o.y = (unsigned)f2bf(s2) | ((unsigned)f2bf(s3) << 16);
    o.z = (unsigned)f2bf(s4) | ((unsigned)f2bf(s5) << 16);
    o.w = (unsigned)f2bf(s6) | ((unsigned)f2bf(s7) << 16);
    *(uint4*)(agg_bf + (size_t)node * 96 + g) = o;
}

// ---------------------------------------------------------------------------
// Fused GRU — weight-stationary, no LDS, no barriers, no races.
// Block = 128 thr (2 waves); wave owns 32 nodes exclusively; data frags
// ([agg|h], 12 x s8v) held in regs (all h reads precede all h writes).
// Loop jb 0..5: 24 lane-contiguous W-frag L2 reads + 48 MFMA; lane-local
// GRUCell epilogue with float4 h read-modify-write.
// ---------------------------------------------------------------------------
__global__ __launch_bounds__(128) void gru_mfma(
    const unsigned short* __restrict__ agg_bf,
    const unsigned short* __restrict__ Wgp,
    const float* __restrict__ bs,
    float* __restrict__ h)
{
    int wave = threadIdx.x >> 6;
    int lane = threadIdx.x & 63;
    int quad = lane >> 4;
    int lc   = lane & 15;
    int nT0  = blockIdx.x * 4 + wave * 2;    // node-tile base (16 nodes/tile)

    s8v d[2][6];
    #pragma unroll
    for (int t = 0; t < 2; t++) {
        int node = (nT0 + t) * 16 + lc;
        #pragma unroll
        for (int ks = 0; ks < 3; ks++)
            d[t][ks] = *(const s8v*)(agg_bf + (size_t)node * 96 + ks * 32 + quad * 8);
        #pragma unroll
        for (int ks = 0; ks < 3; ks++)
            d[t][3 + ks] = load_bf8(h + (size_t)node * 96 + ks * 32 + quad * 8);
    }

    for (int jb = 0; jb < 6; jb++) {
        f4v acc[2][4] = {};
        #pragma unroll
        for (int g = 0; g < 4; g++) {
            const unsigned short* wb = Wgp + ((size_t)(jb * 4 + g) * 6 * 64) * 8;
            #pragma unroll
            for (int ks = 0; ks < 6; ks++) {
                s8v w = *(const s8v*)(wb + ((size_t)ks * 64 + lane) * 8);
                acc[0][g] = __builtin_amdgcn_mfma_f32_16x16x32_bf16(w, d[0][ks], acc[0][g], 0, 0, 0);
                acc[1][g] = __builtin_amdgcn_mfma_f32_16x16x32_bf16(w, d[1][ks], acc[1][g], 0, 0, 0);
            }
        }
        const float* bp = bs + jb * 16 + quad * 4;
        float4 br  = *(const float4*)(bp);
        float4 bz  = *(const float4*)(bp + 96);
        float4 bin = *(const float4*)(bp + 192);
        float4 bhn = *(const float4*)(bp + 288);
        float brv[4]  = {br.x, br.y, br.z, br.w};
        float bzv[4]  = {bz.x, bz.y, bz.z, bz.w};
        float binv[4] = {bin.x, bin.y, bin.z, bin.w};
        float bhnv[4] = {bhn.x, bhn.y, bhn.z, bhn.w};
        #pragma unroll
        for (int t = 0; t < 2; t++) {
            int node = (nT0 + t) * 16 + lc;
            float* hp = h + (size_t)node * 96 + jb * 16 + quad * 4;
            float4 hold = *(const float4*)hp;
            float hv[4] = {hold.x, hold.y, hold.z, hold.w};
            float out[4];
            #pragma unroll
            for (int i = 0; i < 4; i++) {
                float rg = sigmoidf_(acc[t][0][i] + brv[i]);
                float zg = sigmoidf_(acc[t][1][i] + bzv[i]);
                float nn = tanhf_(acc[t][2][i] + binv[i] + rg * (acc[t][3][i] + bhnv[i]));
                out[i] = (1.f - zg) * nn + zg * hv[i];
            }
            *(float4*)hp = make_float4(out[0], out[1], out[2], out[3]);
        }
    }
}

// ---------------------------------------------------------------------------
// Mean pool via sorted-batch segments: one block per graph, no atomics.
// ---------------------------------------------------------------------------
__global__ __launch_bounds__(128) void pool_csr_k(
    const float* __restrict__ h, const int* __restrict__ rpb, float* __restrict__ g)
{
    int b = blockIdx.x;
    int j = threadIdx.x;
    if (j >= 96) return;
    int n0 = rpb[b], n1 = rpb[b + 1];
    float s = 0.f;
    for (int n = n0; n < n1; n++) s += fmaxf(h[(size_t)n * 96 + j], 0.f);
    float c = (float)(n1 - n0);
    g[(size_t)b * 96 + j] = s / fmaxf(c, 1.f);
}

__global__ void feat_k(const float* __restrict__ g1, const float* __restrict__ g2,
                       const float* __restrict__ g3, float* __restrict__ feat)
{
    int idx = blockIdx.x * 256 + threadIdx.x;
    if (idx >= BB * HH) return;
    int b = idx / HH, j = idx % HH;
    float a = g1[idx], bb = g2[idx], c = g3[idx];
    float* f = feat + (size_t)b * 384;
    f[j]       = a;
    f[96 + j]  = bb;
    f[192 + j] = c;
    f[288 + j] = a * bb * c;
}

// ---------------------------------------------------------------------------
// MLP GEMM: C[M,N] = relu(bf16(A[M,K]) @ Bp + bias).
// ---------------------------------------------------------------------------
__global__ __launch_bounds__(256) void gemm_mlp_mfma(
    const float* __restrict__ A, const unsigned short* __restrict__ Bp,
    const float* __restrict__ bias, float* __restrict__ C,
    int K, int N, int doRelu)
{
    int wave = threadIdx.x >> 6;
    int lane = threadIdx.x & 63;
    int quad = lane >> 4;
    int lc   = lane & 15;
    int rowA = blockIdx.y * 64 + wave * 16 + lc;
    int colb = blockIdx.x * 128;

    f4v acc[8] = {};
    for (int ks = 0; ks < K / 32; ks++) {
        s8v a = load_bf8(A + (size_t)rowA * K + ks * 32 + quad * 8);
        #pragma unroll
        for (int t = 0; t < 8; t++) {
            int n = colb + t * 16 + lc;
            s8v b = *(const s8v*)(Bp + ((size_t)(ks * N + n) * 4 + quad) * 8);
            acc[t] = __builtin_amdgcn_mfma_f32_16x16x32_bf16(a, b, acc[t], 0, 0, 0);
        }
    }
    int rowD = blockIdx.y * 64 + wave * 16 + quad * 4;
    #pragma unroll
    for (int t = 0; t < 8; t++) {
        int n = colb + t * 16 + lc;
        float bv = bias[n];
        #pragma unroll
        for (int r = 0; r < 4; r++) {
            float v = acc[t][r] + bv;
            if (doRelu) v = fmaxf(v, 0.f);
            C[(size_t)(rowD + r) * N + n] = v;
        }
    }
}

// fc3: one wave per graph, shuffle reduction.
__global__ __launch_bounds__(256) void fc3_k(const float* __restrict__ t2,
                                             const float* __restrict__ w,
                                             const float* __restrict__ bias,
                                             float* __restrict__ out)
{
    int wave = threadIdx.x >> 6;
    int lane = threadIdx.x & 63;
    int b = blockIdx.x * 4 + wave;
    const float* row = t2 + (size_t)b * 384;
    float a0 = 0.f, a1 = 0.f, a2 = 0.f;
    #pragma unroll
    for (int kk = 0; kk < 6; kk++) {
        int k = kk * 64 + lane;
        float x = row[k];
        a0 += x * w[k * 3 + 0];
        a1 += x * w[k * 3 + 1];
        a2 += x * w[k * 3 + 2];
    }
    #pragma unroll
    for (int off = 32; off > 0; off >>= 1) {
        a0 += __shfl_down(a0, off);
        a1 += __shfl_down(a1, off);
        a2 += __shfl_down(a2, off);
    }
    if (lane == 0) {
        out[b * 3 + 0] = a0 + bias[0];
        out[b * 3 + 1] = a1 + bias[1];
        out[b * 3 + 2] = a2 + bias[2];
    }
}

extern "C" void kernel_launch(void* const* d_in, const int* in_sizes, int n_in,
                              void* d_out, int out_size, void* d_ws, size_t ws_size,
                              hipStream_t stream)
{
    // Workspace (floats). Total ~41.3M f = 165 MB (237 MB proven safe).
    float* ws    = (float*)d_ws;
    float* h     = ws;                               // 19,200,000
    float* mbfF  = h + (size_t)NN_ * HH;             //  9,600,000 (19.2M bf16)
    float* abfF  = mbfF + (size_t)NN_ * HH / 2;      //  9,600,000 (19.2M bf16)
    float* wpF   = abfF + (size_t)NN_ * HH / 2;      //     27,648
    float* wgpF  = wpF + 27648;                      //     36,864
    float* fc1pF = wgpF + 36864;                     //    294,912 (589,824 bf16)
    float* fc2pF = fc1pF + 294912;                   //    294,912
    float* g3    = fc2pF + 294912;                   //  1,179,648
    int*   rp    = (int*)(g3 + 3 * (size_t)BB * HH); //    200,064 ints
    int*   srcs  = rp + 200064;                      //    400,000 ints
    int*   deg   = srcs + 400000;                    //    200,000 ints
    int*   cur   = deg + 200000;                     //    200,000 ints
    int*   bsum  = cur + 200000;                     //        256 ints
    int*   rpb   = bsum + 256;                       //      4,097 ints
    float* bs    = (float*)(rpb + 4097) + 1;         //        384 f (16B-aligned region)

    unsigned short* m_bf   = (unsigned short*)mbfF;
    unsigned short* agg_bf = (unsigned short*)abfF;
    unsigned short* Wp     = (unsigned short*)wpF;
    unsigned short* Wgp    = (unsigned short*)wgpF;
    unsigned short* fc1p   = (unsigned short*)fc1pF;
    unsigned short* fc2p   = (unsigned short*)fc2pF;

    // MLP temps alias h (dead after pooling)
    float* feat = h;
    float* t1   = h + 2 * 1024 * 1024;
    float* t2   = h + 9 * 1024 * 1024;

    for (int c = 0; c < 3; c++) {
        const float* x   = (const float*)d_in[c * 8 + 0];
        const int*   ei  = (const int*)  d_in[c * 8 + 1];
        const int*   bat = (const int*)  d_in[c * 8 + 2];
        const float* W   = (const float*)d_in[c * 8 + 3];
        const float* wih = (const float*)d_in[c * 8 + 4];
        const float* whh = (const float*)d_in[c * 8 + 5];
        const float* bih = (const float*)d_in[c * 8 + 6];
        const float* bhh = (const float*)d_in[c * 8 + 7];

        // CSR build (once per component, reused for all 6 layers)
        hipMemsetAsync(deg, 0, NN_ * sizeof(int), stream);
        deg_k<<<cdiv(EE_, 256), 256, 0, stream>>>(ei, deg);
        scan1_k<<<NB_SCAN, SCAN_B, 0, stream>>>(deg, rp, bsum);
        scan2_k<<<1, 256, 0, stream>>>(bsum);
        scan3_k<<<cdiv(NN_, 256), 256, 0, stream>>>(rp, bsum, cur);
        fill_k<<<cdiv(EE_, 256), 256, 0, stream>>>(ei, cur, srcs);
        brp_k<<<cdiv(NN_, 256), 256, 0, stream>>>(bat, rpb);

        packWp_k<<<cdiv(LL * 6 * 3 * 64 * 8, 256), 256, 0, stream>>>(W, Wp);
        packWgp_k<<<cdiv(24 * 6 * 64 * 8, 256), 256, 0, stream>>>(wih, whh, Wgp);
        bpack_k<<<1, 128, 0, stream>>>(bih, bhh, bs);
        pad_k<<<cdiv(NN_ * HH, 256), 256, 0, stream>>>(x, h);

        for (int l = 0; l < LL; l++) {
            gemm1_mfma<<<NN_ / 64, 128, 0, stream>>>(h, Wp + (size_t)l * 9216, m_bf);
            agg_csr_k<<<cdiv(NN_ * 12, 256), 256, 0, stream>>>(m_bf, rp, srcs, agg_bf);
            gru_mfma<<<NN_ / 64, 128, 0, stream>>>(agg_bf, Wgp, bs, h);
        }

        pool_csr_k<<<BB, 128, 0, stream>>>(h, rpb, g3 + (size_t)c * BB * HH);
    }

    const float* fc1_w = (const float*)d_in[24];
    const float* fc1_b = (const float*)d_in[25];
    const float* fc2_w = (const float*)d_in[26];
    const float* fc2_b = (const float*)d_in[27];
    const float* fc3_w = (const float*)d_in[28];
    const float* fc3_b = (const float*)d_in[29];

    packB_k<<<cdiv(384 * 1536, 256), 256, 0, stream>>>(fc1_w, fc1p, 384, 1536);
    packB_k<<<cdiv(1536 * 384, 256), 256, 0, stream>>>(fc2_w, fc2p, 1536, 384);

    feat_k<<<cdiv(BB * HH, 256), 256, 0, stream>>>(
        g3, g3 + (size_t)BB * HH, g3 + 2 * (size_t)BB * HH, feat);
    gemm_mlp_mfma<<<dim3(1536 / 128, BB / 64), 256, 0, stream>>>(
        feat, fc1p, fc1_b, t1, 384, 1536, 1);
    gemm_mlp_mfma<<<dim3(384 / 128, BB / 64), 256, 0, stream>>>(
        t1, fc2p, fc2_b, t2, 1536, 384, 1);
    fc3_k<<<BB / 4, 256, 0, stream>>>(t2, fc3_w, fc3_b, (float*)d_out);
}

// Round 10
// 2939.441 us; speedup vs baseline: 1.5877x; 1.1982x over previous
//
#include <hip/hip_runtime.h>
#include <math.h>

#define NN_ 200000
#define EE_ 400000
#define HH  96
#define LL  6
#define BB  4096
#define SCAN_B 1024
#define NB_SCAN 196   // cdiv(200000, 1024)

typedef short s8v __attribute__((ext_vector_type(8)));
typedef float f4v __attribute__((ext_vector_type(4)));

static inline int cdiv(int a, int b) { return (a + b - 1) / b; }

__device__ __forceinline__ float sigmoidf_(float x) { return 1.0f / (1.0f + __expf(-x)); }
__device__ __forceinline__ float tanhf_(float x) { return 1.0f - 2.0f / (__expf(2.0f * x) + 1.0f); }
__device__ __forceinline__ unsigned short f2bf(float x) {
    unsigned u = __float_as_uint(x);
    unsigned r = u + 0x7FFF + ((u >> 16) & 1);   // RNE
    return (unsigned short)(r >> 16);
}
__device__ __forceinline__ float bf2f(unsigned short u) {
    return __uint_as_float(((unsigned)u) << 16);
}
// load 8 consecutive fp32 and convert to a bf16x8 MFMA fragment (in-register)
__device__ __forceinline__ s8v load_bf8(const float* __restrict__ p) {
    float4 v0 = *(const float4*)p;
    float4 v1 = *(const float4*)(p + 4);
    s8v r;
    r[0] = (short)f2bf(v0.x); r[1] = (short)f2bf(v0.y);
    r[2] = (short)f2bf(v0.z); r[3] = (short)f2bf(v0.w);
    r[4] = (short)f2bf(v1.x); r[5] = (short)f2bf(v1.y);
    r[6] = (short)f2bf(v1.z); r[7] = (short)f2bf(v1.w);
    return r;
}

// ---------------------------------------------------------------------------
// MLP weight pack (B-operand fragment order, read from global):
// Bp[((k>>5)*N + n)*32 + ((k>>3)&3)*8 + (k&7)] = bf16(B[k*N + n])
// ---------------------------------------------------------------------------
__global__ void packB_k(const float* __restrict__ B, unsigned short* __restrict__ Bp,
                        int K, int N)
{
    int idx = blockIdx.x * 256 + threadIdx.x;
    if (idx >= K * N) return;
    int k = idx / N, n = idx % N;
    Bp[(((size_t)(k >> 5) * N + n) * 4 + ((k >> 3) & 3)) * 8 + (k & 7)] = f2bf(B[idx]);
}

// ---------------------------------------------------------------------------
// Wp pack, weight-stationary A-operand order:
// offset = (((l*6 + jb)*3 + ks)*64 + lane)*8 + j
//   holds  W[l][k = ks*32 + (lane>>4)*8 + j][n = jb*16 + (lane&15)]
// ---------------------------------------------------------------------------
__global__ void packWp_k(const float* __restrict__ W, unsigned short* __restrict__ Wp)
{
    int idx = blockIdx.x * 256 + threadIdx.x;
    if (idx >= LL * 6 * 3 * 64 * 8) return;
    int j    = idx & 7;
    int lane = (idx >> 3) & 63;
    int rest = idx >> 9;
    int ks = rest % 3;
    int jb = (rest / 3) % 6;
    int l  = rest / 18;
    int quad = lane >> 4, lc = lane & 15;
    int k = ks * 32 + quad * 8 + j;
    int n = jb * 16 + lc;
    Wp[idx] = f2bf(W[(size_t)l * 9216 + (size_t)k * 96 + n]);
}

// ---------------------------------------------------------------------------
// Wgp pack, weight-stationary A-operand order, gate-interleaved:
// T = jb*4 + g;  offset = ((T*6 + ks)*64 + lane)*8 + j
//   holds  Wg[k = ks*32 + quad*8 + j][n = g*96 + jb*16 + lc]
// Wg semantics: k<96 from wih (agg side), k>=96 from whh (h side);
// n in [0,192): r/z sums; [192,288): i_n (wih only); [288,384): h_n (whh only)
// ---------------------------------------------------------------------------
__global__ void packWgp_k(const float* __restrict__ wih, const float* __restrict__ whh,
                          unsigned short* __restrict__ Wgp)
{
    int idx = blockIdx.x * 256 + threadIdx.x;
    if (idx >= 24 * 6 * 64 * 8) return;
    int j    = idx & 7;
    int lane = (idx >> 3) & 63;
    int rest = idx >> 9;
    int ks = rest % 6;
    int T  = rest / 6;
    int quad = lane >> 4, lc = lane & 15;
    int g = T & 3, jb = T >> 2;
    int k = ks * 32 + quad * 8 + j;
    int n = g * 96 + jb * 16 + lc;
    float v;
    if (n < 192) {
        v = (k < 96) ? wih[(size_t)n * 96 + k] : whh[(size_t)n * 96 + (k - 96)];
    } else if (n < 288) {
        int jj = n - 192;
        v = (k < 96) ? wih[(size_t)(192 + jj) * 96 + k] : 0.f;
    } else {
        int jj = n - 288;
        v = (k < 96) ? 0.f : whh[(size_t)(192 + jj) * 96 + (k - 96)];
    }
    Wgp[idx] = f2bf(v);
}

// combined bias pack: bs[0..95]=bih_r+bhh_r, [96..191]=bih_z+bhh_z,
// [192..287]=bih_n, [288..383]=bhh_n
__global__ void bpack_k(const float* __restrict__ bih, const float* __restrict__ bhh,
                        float* __restrict__ bs)
{
    int j = threadIdx.x;
    if (j >= 96) return;
    bs[j]        = bih[j] + bhh[j];
    bs[96 + j]   = bih[96 + j] + bhh[96 + j];
    bs[192 + j]  = bih[192 + j];
    bs[288 + j]  = bhh[192 + j];
}

__global__ void pad_k(const float* __restrict__ x, float* __restrict__ h,
                      unsigned short* __restrict__ hbf)
{
    int idx = blockIdx.x * 256 + threadIdx.x;
    if (idx >= NN_ * HH) return;
    int n = idx / HH, j = idx % HH;
    float v = (j < 32) ? x[n * 32 + j] : 0.f;
    h[idx] = v;
    hbf[idx] = f2bf(v);
}

// --------------------------- CSR build (once per component) -----------------
__global__ void deg_k(const int* __restrict__ ei, int* __restrict__ deg)
{
    int e = blockIdx.x * 256 + threadIdx.x;
    if (e >= EE_) return;
    atomicAdd(&deg[ei[EE_ + e]], 1);
}

__global__ __launch_bounds__(SCAN_B) void scan1_k(
    const int* __restrict__ deg, int* __restrict__ rp, int* __restrict__ bsum)
{
    __shared__ int sh[SCAN_B];
    int i = blockIdx.x * SCAN_B + threadIdx.x;
    int v = (i < NN_) ? deg[i] : 0;
    sh[threadIdx.x] = v;
    __syncthreads();
    for (int off = 1; off < SCAN_B; off <<= 1) {
        int t = (threadIdx.x >= off) ? sh[threadIdx.x - off] : 0;
        __syncthreads();
        sh[threadIdx.x] += t;
        __syncthreads();
    }
    if (i < NN_) rp[i] = sh[threadIdx.x] - v;     // exclusive within block
    if (threadIdx.x == SCAN_B - 1) bsum[blockIdx.x] = sh[threadIdx.x];
}

__global__ __launch_bounds__(256) void scan2_k(int* __restrict__ bsum)
{
    __shared__ int sh[256];
    int v = (threadIdx.x < NB_SCAN) ? bsum[threadIdx.x] : 0;
    sh[threadIdx.x] = v;
    __syncthreads();
    for (int off = 1; off < 256; off <<= 1) {
        int t = (threadIdx.x >= off) ? sh[threadIdx.x - off] : 0;
        __syncthreads();
        sh[threadIdx.x] += t;
        __syncthreads();
    }
    if (threadIdx.x < NB_SCAN) bsum[threadIdx.x] = sh[threadIdx.x] - v;  // exclusive
}

__global__ void scan3_k(int* __restrict__ rp, const int* __restrict__ bsum,
                        int* __restrict__ cur)
{
    int i = blockIdx.x * 256 + threadIdx.x;
    if (i < NN_) {
        int r = rp[i] + bsum[i / SCAN_B];
        rp[i] = r;
        cur[i] = r;
    }
    if (i == 0) rp[NN_] = EE_;
}

__global__ void fill_k(const int* __restrict__ ei, int* __restrict__ cur,
                       int* __restrict__ srcs)
{
    int e = blockIdx.x * 256 + threadIdx.x;
    if (e >= EE_) return;
    int s = ei[e];
    int d = ei[EE_ + e];
    int pos = atomicAdd(&cur[d], 1);
    srcs[pos] = s;
}

// batch row pointers: batch[] is sorted, detect segment boundaries.
__global__ void brp_k(const int* __restrict__ bat, int* __restrict__ rpb)
{
    int i = blockIdx.x * 256 + threadIdx.x;
    if (i >= NN_) return;
    int b = bat[i];
    if (i == 0) {
        for (int q = 0; q <= b; q++) rpb[q] = 0;
    } else {
        int p = bat[i - 1];
        for (int q = p + 1; q <= b; q++) rpb[q] = i;
    }
    if (i == NN_ - 1) {
        for (int q = b + 1; q <= BB; q++) rpb[q] = NN_;
    }
}

// ---------------------------------------------------------------------------
// Fully fused GGC layer (ONE dispatch per layer). Uses linearity:
//   agg = sum_src(h W) = (sum_src h) W.
// Block = 128 thr (2 waves); wave owns 32 nodes (2 tiles of 16) exclusively.
//   Stage 0: per-lane CSR gather-sum of hbf_prev -> hagg frags (fp32 acc, bf16)
//   Stage 1: agg = hagg @ W[l]  (weight-stationary MFMA) -> wave-local LDS
//            transpose (D-layout -> B-operand layout), bf16
//   Stage 2: load agg frags (LDS) + h frags (hbf_prev)
//   Stage 3: G = [agg|h] @ Wg, lane-local GRUCell epilogue, write h (fp32)
//            and hbf_next (bf16).
// No barriers (all LDS traffic wave-local); hbf ping-pongs across layers so
// other blocks' gathers only ever see prev-layer values.
// ---------------------------------------------------------------------------
__global__ __launch_bounds__(128) void layer_k(
    const int* __restrict__ rp, const int* __restrict__ srcs,
    const unsigned short* __restrict__ hbf_prev,
    const unsigned short* __restrict__ Wp,   // this layer: [6][3][64][8]
    const unsigned short* __restrict__ Wgp,  // [24][6][64][8]
    const float* __restrict__ bs,
    float* __restrict__ h,
    unsigned short* __restrict__ hbf_next)
{
    __shared__ unsigned short as_[2][32][104];   // 13,312 B; [wave][node][feat+pad]
    int tid  = threadIdx.x;
    int wave = tid >> 6;
    int lane = tid & 63;
    int quad = lane >> 4;
    int lc   = lane & 15;
    int nT0  = blockIdx.x * 4 + wave * 2;        // node-tile base (16 nodes/tile)

    // ---- Stage 0: gather hagg = sum over in-edges of hbf_prev ----
    s8v hg[2][3];
    #pragma unroll
    for (int t = 0; t < 2; t++) {
        int node = (nT0 + t) * 16 + lc;
        float ag[24];
        #pragma unroll
        for (int i = 0; i < 24; i++) ag[i] = 0.f;
        int e0 = rp[node], e1 = rp[node + 1];
        for (int e = e0; e < e1; e++) {
            int sr = srcs[e];
            const unsigned short* rowp = hbf_prev + (size_t)sr * 96 + quad * 8;
            #pragma unroll
            for (int ks = 0; ks < 3; ks++) {
                uint4 u = *(const uint4*)(rowp + ks * 32);
                ag[ks * 8 + 0] += bf2f((unsigned short)(u.x & 0xFFFF));
                ag[ks * 8 + 1] += bf2f((unsigned short)(u.x >> 16));
                ag[ks * 8 + 2] += bf2f((unsigned short)(u.y & 0xFFFF));
                ag[ks * 8 + 3] += bf2f((unsigned short)(u.y >> 16));
                ag[ks * 8 + 4] += bf2f((unsigned short)(u.z & 0xFFFF));
                ag[ks * 8 + 5] += bf2f((unsigned short)(u.z >> 16));
                ag[ks * 8 + 6] += bf2f((unsigned short)(u.w & 0xFFFF));
                ag[ks * 8 + 7] += bf2f((unsigned short)(u.w >> 16));
            }
        }
        #pragma unroll
        for (int ks = 0; ks < 3; ks++) {
            s8v v;
            #pragma unroll
            for (int j = 0; j < 8; j++) v[j] = (short)f2bf(ag[ks * 8 + j]);
            hg[t][ks] = v;
        }
    }

    // ---- Stage 1: agg = hagg @ W -> LDS transpose (bf16) ----
    for (int jb = 0; jb < 6; jb++) {
        f4v a1[2] = {};
        #pragma unroll
        for (int ks = 0; ks < 3; ks++) {
            s8v w = *(const s8v*)(Wp + ((size_t)(jb * 3 + ks) * 64 + lane) * 8);
            a1[0] = __builtin_amdgcn_mfma_f32_16x16x32_bf16(w, hg[0][ks], a1[0], 0, 0, 0);
            a1[1] = __builtin_amdgcn_mfma_f32_16x16x32_bf16(w, hg[1][ks], a1[1], 0, 0, 0);
        }
        #pragma unroll
        for (int t = 0; t < 2; t++) {
            unsigned short o0 = f2bf(a1[t][0]), o1 = f2bf(a1[t][1]);
            unsigned short o2 = f2bf(a1[t][2]), o3 = f2bf(a1[t][3]);
            *(uint2*)&as_[wave][t * 16 + lc][jb * 16 + quad * 4] =
                make_uint2((unsigned)o0 | ((unsigned)o1 << 16),
                           (unsigned)o2 | ((unsigned)o3 << 16));
        }
    }

    // ---- Stage 2: data fragments for the G-GEMM ----
    s8v d[2][6];
    #pragma unroll
    for (int t = 0; t < 2; t++) {
        int node = (nT0 + t) * 16 + lc;
        #pragma unroll
        for (int ks = 0; ks < 3; ks++)
            d[t][ks] = *(const s8v*)&as_[wave][t * 16 + lc][ks * 32 + quad * 8];
        #pragma unroll
        for (int ks = 0; ks < 3; ks++)
            d[t][3 + ks] = *(const s8v*)(hbf_prev + (size_t)node * 96 + ks * 32 + quad * 8);
    }

    // ---- Stage 3: G-GEMM + GRUCell epilogue ----
    for (int jb = 0; jb < 6; jb++) {
        // prefetch h_old (independent of MFMAs below)
        float4 hold[2];
        #pragma unroll
        for (int t = 0; t < 2; t++)
            hold[t] = *(const float4*)(h + (size_t)((nT0 + t) * 16 + lc) * 96 + jb * 16 + quad * 4);
        f4v acc[2][4] = {};
        #pragma unroll
        for (int g = 0; g < 4; g++) {
            const unsigned short* wb = Wgp + (size_t)(jb * 4 + g) * 6 * 64 * 8;
            #pragma unroll
            for (int ks = 0; ks < 6; ks++) {
                s8v w = *(const s8v*)(wb + ((size_t)ks * 64 + lane) * 8);
                acc[0][g] = __builtin_amdgcn_mfma_f32_16x16x32_bf16(w, d[0][ks], acc[0][g], 0, 0, 0);
                acc[1][g] = __builtin_amdgcn_mfma_f32_16x16x32_bf16(w, d[1][ks], acc[1][g], 0, 0, 0);
            }
        }
        const float* bp = bs + jb * 16 + quad * 4;
        float4 br  = *(const float4*)(bp);
        float4 bz  = *(const float4*)(bp + 96);
        float4 bin = *(const float4*)(bp + 192);
        float4 bhn = *(const float4*)(bp + 288);
        float brv[4]  = {br.x, br.y, br.z, br.w};
        float bzv[4]  = {bz.x, bz.y, bz.z, bz.w};
        float binv[4] = {bin.x, bin.y, bin.z, bin.w};
        float bhnv[4] = {bhn.x, bhn.y, bhn.z, bhn.w};
        #pragma unroll
        for (int t = 0; t < 2; t++) {
            int node = (nT0 + t) * 16 + lc;
            float hv[4] = {hold[t].x, hold[t].y, hold[t].z, hold[t].w};
            float out[4];
            #pragma unroll
            for (int i = 0; i < 4; i++) {
                float rg = sigmoidf_(acc[t][0][i] + brv[i]);
                float zg = sigmoidf_(acc[t][1][i] + bzv[i]);
                float nn = tanhf_(acc[t][2][i] + binv[i] + rg * (acc[t][3][i] + bhnv[i]));
                out[i] = (1.f - zg) * nn + zg * hv[i];
            }
            float* hp = h + (size_t)node * 96 + jb * 16 + quad * 4;
            *(float4*)hp = make_float4(out[0], out[1], out[2], out[3]);
            unsigned short q0 = f2bf(out[0]), q1 = f2bf(out[1]);
            unsigned short q2 = f2bf(out[2]), q3 = f2bf(out[3]);
            *(uint2*)(hbf_next + (size_t)node * 96 + jb * 16 + quad * 4) =
                make_uint2((unsigned)q0 | ((unsigned)q1 << 16),
                           (unsigned)q2 | ((unsigned)q3 << 16));
        }
    }
}

// ---------------------------------------------------------------------------
// Mean pool via sorted-batch segments: one block per graph, no atomics.
// ---------------------------------------------------------------------------
__global__ __launch_bounds__(128) void pool_csr_k(
    const float* __restrict__ h, const int* __restrict__ rpb, float* __restrict__ g)
{
    int b = blockIdx.x;
    int j = threadIdx.x;
    if (j >= 96) return;
    int n0 = rpb[b], n1 = rpb[b + 1];
    float s = 0.f;
    for (int n = n0; n < n1; n++) s += fmaxf(h[(size_t)n * 96 + j], 0.f);
    float c = (float)(n1 - n0);
    g[(size_t)b * 96 + j] = s / fmaxf(c, 1.f);
}

__global__ void feat_k(const float* __restrict__ g1, const float* __restrict__ g2,
                       const float* __restrict__ g3, float* __restrict__ feat)
{
    int idx = blockIdx.x * 256 + threadIdx.x;
    if (idx >= BB * HH) return;
    int b = idx / HH, j = idx % HH;
    float a = g1[idx], bb = g2[idx], c = g3[idx];
    float* f = feat + (size_t)b * 384;
    f[j]       = a;
    f[96 + j]  = bb;
    f[192 + j] = c;
    f[288 + j] = a * bb * c;
}

// ---------------------------------------------------------------------------
// MLP GEMM: C[M,N] = relu(bf16(A[M,K]) @ Bp + bias).
// ---------------------------------------------------------------------------
__global__ __launch_bounds__(256) void gemm_mlp_mfma(
    const float* __restrict__ A, const unsigned short* __restrict__ Bp,
    const float* __restrict__ bias, float* __restrict__ C,
    int K, int N, int doRelu)
{
    int wave = threadIdx.x >> 6;
    int lane = threadIdx.x & 63;
    int quad = lane >> 4;
    int lc   = lane & 15;
    int rowA = blockIdx.y * 64 + wave * 16 + lc;
    int colb = blockIdx.x * 128;

    f4v acc[8] = {};
    for (int ks = 0; ks < K / 32; ks++) {
        s8v a = load_bf8(A + (size_t)rowA * K + ks * 32 + quad * 8);
        #pragma unroll
        for (int t = 0; t < 8; t++) {
            int n = colb + t * 16 + lc;
            s8v b = *(const s8v*)(Bp + ((size_t)(ks * N + n) * 4 + quad) * 8);
            acc[t] = __builtin_amdgcn_mfma_f32_16x16x32_bf16(a, b, acc[t], 0, 0, 0);
        }
    }
    int rowD = blockIdx.y * 64 + wave * 16 + quad * 4;
    #pragma unroll
    for (int t = 0; t < 8; t++) {
        int n = colb + t * 16 + lc;
        float bv = bias[n];
        #pragma unroll
        for (int r = 0; r < 4; r++) {
            float v = acc[t][r] + bv;
            if (doRelu) v = fmaxf(v, 0.f);
            C[(size_t)(rowD + r) * N + n] = v;
        }
    }
}

// fc3: one wave per graph, shuffle reduction.
__global__ __launch_bounds__(256) void fc3_k(const float* __restrict__ t2,
                                             const float* __restrict__ w,
                                             const float* __restrict__ bias,
                                             float* __restrict__ out)
{
    int wave = threadIdx.x >> 6;
    int lane = threadIdx.x & 63;
    int b = blockIdx.x * 4 + wave;
    const float* row = t2 + (size_t)b * 384;
    float a0 = 0.f, a1 = 0.f, a2 = 0.f;
    #pragma unroll
    for (int kk = 0; kk < 6; kk++) {
        int k = kk * 64 + lane;
        float x = row[k];
        a0 += x * w[k * 3 + 0];
        a1 += x * w[k * 3 + 1];
        a2 += x * w[k * 3 + 2];
    }
    #pragma unroll
    for (int off = 32; off > 0; off >>= 1) {
        a0 += __shfl_down(a0, off);
        a1 += __shfl_down(a1, off);
        a2 += __shfl_down(a2, off);
    }
    if (lane == 0) {
        out[b * 3 + 0] = a0 + bias[0];
        out[b * 3 + 1] = a1 + bias[1];
        out[b * 3 + 2] = a2 + bias[2];
    }
}

extern "C" void kernel_launch(void* const* d_in, const int* in_sizes, int n_in,
                              void* d_out, int out_size, void* d_ws, size_t ws_size,
                              hipStream_t stream)
{
    // Workspace (floats). Total ~41.5M f ≈ 166 MB (237 MB proven safe).
    float* ws    = (float*)d_ws;
    float* h     = ws;                               // 19,200,000
    float* hbfAF = h + (size_t)NN_ * HH;             //  9,600,000 (19.2M bf16)
    float* hbfBF = hbfAF + (size_t)NN_ * HH / 2;     //  9,600,000 (19.2M bf16)
    float* wpF   = hbfBF + (size_t)NN_ * HH / 2;     //     27,648
    float* wgpF  = wpF + 27648;                      //     36,864
    float* fc1pF = wgpF + 36864;                     //    294,912 (589,824 bf16)
    float* fc2pF = fc1pF + 294912;                   //    294,912
    float* g3    = fc2pF + 294912;                   //  1,179,648
    int*   rp    = (int*)(g3 + 3 * (size_t)BB * HH); //    200,064 ints
    int*   srcs  = rp + 200064;                      //    400,000 ints
    int*   deg   = srcs + 400000;                    //    200,000 ints
    int*   cur   = deg + 200000;                     //    200,000 ints
    int*   bsum  = cur + 200000;                     //        256 ints
    int*   rpb   = bsum + 256;                       //      4,097 ints
    float* bs    = (float*)(rpb + 4097) + 1;         //        384 f (16B-aligned region)

    unsigned short* hbfA = (unsigned short*)hbfAF;
    unsigned short* hbfB = (unsigned short*)hbfBF;
    unsigned short* Wp   = (unsigned short*)wpF;
    unsigned short* Wgp  = (unsigned short*)wgpF;
    unsigned short* fc1p = (unsigned short*)fc1pF;
    unsigned short* fc2p = (unsigned short*)fc2pF;

    // MLP temps alias h (dead after pooling)
    float* feat = h;
    float* t1   = h + 2 * 1024 * 1024;
    float* t2   = h + 9 * 1024 * 1024;

    for (int c = 0; c < 3; c++) {
        const float* x   = (const float*)d_in[c * 8 + 0];
        const int*   ei  = (const int*)  d_in[c * 8 + 1];
        const int*   bat = (const int*)  d_in[c * 8 + 2];
        const float* W   = (const float*)d_in[c * 8 + 3];
        const float* wih = (const float*)d_in[c * 8 + 4];
        const float* whh = (const float*)d_in[c * 8 + 5];
        const float* bih = (const float*)d_in[c * 8 + 6];
        const float* bhh = (const float*)d_in[c * 8 + 7];

        // CSR build (once per component, reused for all 6 layers)
        hipMemsetAsync(deg, 0, NN_ * sizeof(int), stream);
        deg_k<<<cdiv(EE_, 256), 256, 0, stream>>>(ei, deg);
        scan1_k<<<NB_SCAN, SCAN_B, 0, stream>>>(deg, rp, bsum);
        scan2_k<<<1, 256, 0, stream>>>(bsum);
        scan3_k<<<cdiv(NN_, 256), 256, 0, stream>>>(rp, bsum, cur);
        fill_k<<<cdiv(EE_, 256), 256, 0, stream>>>(ei, cur, srcs);
        brp_k<<<cdiv(NN_, 256), 256, 0, stream>>>(bat, rpb);

        packWp_k<<<cdiv(LL * 6 * 3 * 64 * 8, 256), 256, 0, stream>>>(W, Wp);
        packWgp_k<<<cdiv(24 * 6 * 64 * 8, 256), 256, 0, stream>>>(wih, whh, Wgp);
        bpack_k<<<1, 128, 0, stream>>>(bih, bhh, bs);
        pad_k<<<cdiv(NN_ * HH, 256), 256, 0, stream>>>(x, h, hbfA);

        unsigned short* pb[2] = {hbfA, hbfB};
        for (int l = 0; l < LL; l++) {
            layer_k<<<NN_ / 64, 128, 0, stream>>>(
                rp, srcs, pb[l & 1], Wp + (size_t)l * 9216, Wgp, bs, h, pb[(l + 1) & 1]);
        }

        pool_csr_k<<<BB, 128, 0, stream>>>(h, rpb, g3 + (size_t)c * BB * HH);
    }

    const float* fc1_w = (const float*)d_in[24];
    const float* fc1_b = (const float*)d_in[25];
    const float* fc2_w = (const float*)d_in[26];
    const float* fc2_b = (const float*)d_in[27];
    const float* fc3_w = (const float*)d_in[28];
    const float* fc3_b = (const float*)d_in[29];

    packB_k<<<cdiv(384 * 1536, 256), 256, 0, stream>>>(fc1_w, fc1p, 384, 1536);
    packB_k<<<cdiv(1536 * 384, 256), 256, 0, stream>>>(fc2_w, fc2p, 1536, 384);

    feat_k<<<cdiv(BB * HH, 256), 256, 0, stream>>>(
        g3, g3 + (size_t)BB * HH, g3 + 2 * (size_t)BB * HH, feat);
    gemm_mlp_mfma<<<dim3(1536 / 128, BB / 64), 256, 0, stream>>>(
        feat, fc1p, fc1_b, t1, 384, 1536, 1);
    gemm_mlp_mfma<<<dim3(384 / 128, BB / 64), 256, 0, stream>>>(
        t1, fc2p, fc2_b, t2, 1536, 384, 1);
    fc3_k<<<BB / 4, 256, 0, stream>>>(t2, fc3_w, fc3_b, (float*)d_out);
}